// Round 9
// baseline (40.041 us; speedup 1.0000x reference)
//
#include <hip/hip_runtime.h>
#include <hip/hip_fp16.h>

#define DIN 1024
#define H_SZ 512
#define OUT_SZ 512
#define EPSF 1e-8f

typedef __attribute__((ext_vector_type(8))) short short8v;   // 8 bf16 = 4 VGPRs
typedef __attribute__((ext_vector_type(4))) float f32x4;
typedef _Float16 half2v __attribute__((ext_vector_type(2)));

// fp32 -> bf16 (RNE)
static __device__ inline unsigned short f2bf(float f) {
    unsigned u = __float_as_uint(f);
    u = u + 0x7FFFu + ((u >> 16) & 1u);
    return (unsigned short)(u >> 16);
}

// Canberra core: 6 packed ops per 2 terms (proven rounds 3/5/6/8, absmax 1.5e-5).
static __device__ inline void canb2(unsigned hu, unsigned wu, unsigned& a, unsigned two) {
    unsigned mn, sm, tt, y;
    asm("v_pk_min_f16 %0, %1, %2" : "=v"(mn) : "v"(hu), "v"(wu));
    asm("v_pk_add_f16 %0, %1, %2" : "=v"(sm) : "v"(hu), "v"(wu));
    y = 0x77847784u - sm;                           // magic rcp seed (v_sub_u32)
    asm("v_pk_fma_f16 %0, %1, %2, %3 neg_lo:[1,0,0] neg_hi:[1,0,0]"
        : "=v"(tt) : "v"(sm), "v"(y), "v"(two));    // tt = 2 - sm*y
    asm("v_pk_mul_f16 %0, %1, %2" : "=v"(y) : "v"(y), "v"(tt));
    asm("v_pk_fma_f16 %0, %1, %2, %0" : "+v"(a) : "v"(mn), "v"(y));
}

// ---------------- GEMM (r8-proven): 8 waves = 4 quadrants x 2 k-halves ------
// Tile 32x32, BK=64 dbuf per k-half, LDS accumulator exchange.
// 512 blocks x 512 thr = 16 waves/CU. Also does Wd relu-cvt (1 elem/thread).
__global__ __launch_bounds__(512, 4) void gemm8(const float* __restrict__ x,
                                                const float* __restrict__ W1,
                                                const float* __restrict__ b1,
                                                const float* __restrict__ Wd,
                                                unsigned short* __restrict__ hh,
                                                unsigned short* __restrict__ wh) {
    __shared__ unsigned short As[2][2][32][72];   // [khalf][buf][m][k]
    __shared__ unsigned short Bs[2][2][32][72];
    __shared__ float red[4][64][4];
    const int t  = threadIdx.x;
    const int b0 = blockIdx.x * 32;
    const int o0 = blockIdx.y * 32;

    const int w  = t >> 6;
    const int l  = t & 63;
    const int q  = w & 3;
    const int kh = w >> 2;
    const int m0 = (q >> 1) * 16;
    const int n0 = (q & 1) * 16;
    const int lr = l & 15;
    const int lk = (l >> 4) * 8;
    const int th = t & 255;
    const int ar = th >> 3;
    const int ko = (th & 7) * 8;

    f32x4 acc = {0.f, 0.f, 0.f, 0.f};
    const float* arow = &x [(size_t)(b0 + ar) * DIN + kh * 512 + ko];
    const float* brow = &W1[(size_t)(o0 + ar) * DIN + kh * 512 + ko];
    float4 pa0 = *reinterpret_cast<const float4*>(arow);
    float4 pa1 = *reinterpret_cast<const float4*>(arow + 4);
    float4 pb0 = *reinterpret_cast<const float4*>(brow);
    float4 pb1 = *reinterpret_cast<const float4*>(brow + 4);

    for (int k0 = 0; k0 < 512; k0 += 64) {
        const int buf = (k0 >> 6) & 1;
        short8v av, bv;
        av[0] = (short)f2bf(pa0.x); av[1] = (short)f2bf(pa0.y);
        av[2] = (short)f2bf(pa0.z); av[3] = (short)f2bf(pa0.w);
        av[4] = (short)f2bf(pa1.x); av[5] = (short)f2bf(pa1.y);
        av[6] = (short)f2bf(pa1.z); av[7] = (short)f2bf(pa1.w);
        bv[0] = (short)f2bf(pb0.x); bv[1] = (short)f2bf(pb0.y);
        bv[2] = (short)f2bf(pb0.z); bv[3] = (short)f2bf(pb0.w);
        bv[4] = (short)f2bf(pb1.x); bv[5] = (short)f2bf(pb1.y);
        bv[6] = (short)f2bf(pb1.z); bv[7] = (short)f2bf(pb1.w);
        *reinterpret_cast<short8v*>(&As[kh][buf][ar][ko]) = av;
        *reinterpret_cast<short8v*>(&Bs[kh][buf][ar][ko]) = bv;
        __syncthreads();   // dbuf safe: buf^1's last reads were 2 syncs back (proven r5-r8)
        if (k0 + 64 < 512) {
            pa0 = *reinterpret_cast<const float4*>(arow + k0 + 64);
            pa1 = *reinterpret_cast<const float4*>(arow + k0 + 68);
            pb0 = *reinterpret_cast<const float4*>(brow + k0 + 64);
            pb1 = *reinterpret_cast<const float4*>(brow + k0 + 68);
        }
        #pragma unroll
        for (int s = 0; s < 2; ++s) {
            const short8v af = *reinterpret_cast<const short8v*>(&As[kh][buf][m0 + lr][s * 32 + lk]);
            const short8v bf = *reinterpret_cast<const short8v*>(&Bs[kh][buf][n0 + lr][s * 32 + lk]);
            acc = __builtin_amdgcn_mfma_f32_16x16x32_bf16(af, bf, acc, 0, 0, 0);
        }
    }
    __syncthreads();
    if (kh == 1) {
        #pragma unroll
        for (int r = 0; r < 4; ++r) red[q][l][r] = acc[r];
    }
    __syncthreads();
    if (kh == 0) {
        // C/D layout (m89-verified): col = lane&15, row = (lane>>4)*4 + reg
        const int col = o0 + n0 + lr;
        const float bias = b1[col];
        #pragma unroll
        for (int r = 0; r < 4; ++r) {
            const float v = acc[r] + red[q][l][r] + bias;
            const int m = b0 + m0 + (l >> 4) * 4 + r;
            hh[(size_t)m * H_SZ + col] = __half_as_ushort(__float2half(fmaxf(v, 0.0f)));
        }
    }
    // Wd preprocess: 262144 elems == 512 blocks * 512 thr. +0 only (no -0 bits).
    const int gid = (blockIdx.y * 32 + blockIdx.x) * 512 + t;
    const float wv0 = Wd[gid];
    wh[gid] = __half_as_ushort(__float2half(wv0 > 0.f ? wv0 : 0.f));
}

// ---------------- Canberra: dist = 512 - 2*sum(min(h,w')/(h+w')),  sim = 1/dist ----------------
// NEW structure for 8 waves/SIMD: tile 32b x 16o, grid 1024 blocks x 512 thr = 4 blocks/CU
// (2048 thr/CU). k-split-8 (wave-uniform ks = t>>6), thread-tile 4b x 2o (rows bi+8c, cols oj+8d).
// LDS 25.3 KB/block via two 256-k staging chunks. launch_bounds(512,8) caps VGPR at 64;
// live-set ~50 (6 uint4 operands + 8 acc + 2 LDS bases; tile offsets fold into offset: imm).
// Bank math: h-read rows bi+8c stride 132 -> banks 4*bi+... 32 distinct, 8-lane bcast, free.
//            w-read rows oj+8d -> same, free. Staging contiguous b128, free.
__global__ __launch_bounds__(512, 8) void canberra6(const unsigned short* __restrict__ hh,
                                                    const unsigned short* __restrict__ wh,
                                                    float* __restrict__ out) {
    __shared__ unsigned hs[32][132];   // 32 b-rows x 128 uints (256 k) + pad 4
    __shared__ unsigned ws[16][132];   // 16 o-rows x 128 uints + pad 4
    const int t  = threadIdx.x;
    const int b0 = blockIdx.x * 32;
    const int o0 = blockIdx.y * 16;
    const unsigned* hu = reinterpret_cast<const unsigned*>(hh);
    const unsigned* wu = reinterpret_cast<const unsigned*>(wh);

    const int ks = t >> 6;     // 0..7, wave-uniform k-slice
    const int l  = t & 63;
    const int bi = l >> 3;     // 0..7
    const int oj = l & 7;      // 0..7
    const unsigned two = 0x40004000u;   // {2.0h, 2.0h}

    unsigned acc[4][2] = {};

    for (int ch = 0; ch < 2; ++ch) {    // two 256-k chunks
        if (ch) __syncthreads();        // previous chunk's reads complete
        // stage hs: 1024 uint4, 2/thread; ws: 512 uint4, 1/thread (coalesced)
        #pragma unroll
        for (int r = 0; r < 2; ++r) {
            const int s = t + r * 512;
            const int row = s >> 5;         // 0..31
            const int c4  = s & 31;         // uint4 col
            *reinterpret_cast<uint4*>(&hs[row][c4 * 4]) =
                *reinterpret_cast<const uint4*>(&hu[(size_t)(b0 + row) * 256 + ch * 128 + c4 * 4]);
        }
        {
            const int row = t >> 5;         // 0..15
            const int c4  = t & 31;
            *reinterpret_cast<uint4*>(&ws[row][c4 * 4]) =
                *reinterpret_cast<const uint4*>(&wu[(size_t)(o0 + row) * 256 + ch * 128 + c4 * 4]);
        }
        __syncthreads();

        #pragma unroll
        for (int g = 0; g < 4; ++g) {   // 4 uint4-cols = 32 k per thread per chunk
            const int col = ks * 16 + g * 4;
            uint4 hv[4], wv[2];
            #pragma unroll
            for (int c = 0; c < 4; ++c)
                hv[c] = *reinterpret_cast<const uint4*>(&hs[bi + 8 * c][col]);
            #pragma unroll
            for (int d = 0; d < 2; ++d)
                wv[d] = *reinterpret_cast<const uint4*>(&ws[oj + 8 * d][col]);
            #pragma unroll
            for (int c = 0; c < 4; ++c) {
                #pragma unroll
                for (int d = 0; d < 2; ++d) {
                    canb2(hv[c].x, wv[d].x, acc[c][d], two);
                    canb2(hv[c].y, wv[d].y, acc[c][d], two);
                    canb2(hv[c].z, wv[d].z, acc[c][d], two);
                    canb2(hv[c].w, wv[d].w, acc[c][d], two);
                }
            }
        }
    }

    float p[8];
    #pragma unroll
    for (int c = 0; c < 4; ++c)
        #pragma unroll
        for (int d = 0; d < 2; ++d) {
            const half2v av = __builtin_bit_cast(half2v, acc[c][d]);
            p[c * 2 + d] = (float)av.x + (float)av.y;
        }

    // 8-way k-reduce, transposed conflict-free layout (r8-proven): bank = lane%32
    __syncthreads();
    float* red = reinterpret_cast<float*>(&hs[0][0]);   // [8][448] floats = 14.3 KB
    if (ks > 0) {
        const int slot = (ks - 1) * 64 + l;
        #pragma unroll
        for (int i = 0; i < 8; ++i) red[i * 448 + slot] = p[i];
    }
    __syncthreads();
    if (ks == 0) {
        #pragma unroll
        for (int q = 0; q < 7; ++q) {
            #pragma unroll
            for (int i = 0; i < 8; ++i) p[i] += red[i * 448 + q * 64 + l];
        }
        #pragma unroll
        for (int c = 0; c < 4; ++c) {
            #pragma unroll
            for (int d = 0; d < 2; ++d) {
                float dd = 512.0f - 2.0f * p[c * 2 + d] + EPSF;
                dd = fminf(fmaxf(dd, EPSF), 1000000.0f);
                out[(size_t)(b0 + bi + 8 * c) * OUT_SZ + o0 + oj + 8 * d] = 1.0f / dd;
            }
        }
    }
}

extern "C" void kernel_launch(void* const* d_in, const int* in_sizes, int n_in,
                              void* d_out, int out_size, void* d_ws, size_t ws_size,
                              hipStream_t stream) {
    const float* x  = (const float*)d_in[0];
    const float* W1 = (const float*)d_in[1];
    const float* b1 = (const float*)d_in[2];
    const float* Wd = (const float*)d_in[3];
    float* out = (float*)d_out;
    unsigned short* hh = (unsigned short*)d_ws;                          // 1 MB fp16 h
    unsigned short* wh = (unsigned short*)((char*)d_ws + (1u << 20));    // 0.5 MB fp16 relu(Wd)

    gemm8<<<dim3(32, 16), 512, 0, stream>>>(x, W1, b1, Wd, hh, wh);
    canberra6<<<dim3(32, 32), 512, 0, stream>>>(hh, wh, out);
}